// Round 7
// baseline (382.940 us; speedup 1.0000x reference)
//
#include <hip/hip_runtime.h>
#include <hip/hip_bf16.h>

// Shapes fixed by the reference: b=1, c=512, t=16, h=w=32
#define CCH   512
#define NPOS  16384
#define NTOK  1024
#define NFRM  16
#define NGRP  32
#define GSZ   (CCH / NGRP)
#define GELEM (GSZ * NPOS)
#define GN_SPLIT 32

typedef unsigned short u16;
typedef unsigned int   u32;
typedef __attribute__((ext_vector_type(8))) short  short8;
typedef __attribute__((ext_vector_type(4))) float  floatx4;

__device__ __forceinline__ float bf2f(u16 u) {
    return __uint_as_float(((u32)u) << 16);
}
__device__ __forceinline__ u16 f2bf(float f) {
    u32 u = __float_as_uint(f);
    u = (u + 0x7fffu + ((u >> 16) & 1u)) >> 16;
    return (u16)u;
}
__device__ __forceinline__ float ldx(const void* p, size_t i, bool f32m) {
    return f32m ? ((const float*)p)[i] : bf2f(((const u16*)p)[i]);
}

// ------------------------------------------------------------ dtype detect
__launch_bounds__(256)
__global__ void detect_dtype(const u32* __restrict__ x32, u32* __restrict__ flag) {
    __shared__ int cnt;
    if (threadIdx.x == 0) cnt = 0;
    __syncthreads();
    int c = 0;
    for (int i = threadIdx.x; i < 4096; i += 256) {
        u32 v = x32[i] & 0xFFFFu;
        u32 e = (v >> 7) & 0xFFu;
        if (e >= 0xC8u) c++;
    }
    atomicAdd(&cnt, c);
    __syncthreads();
    if (threadIdx.x == 0) *flag = (cnt > 64) ? 1u : 0u;
}

__launch_bounds__(256)
__global__ void conv_bf16(const void* __restrict__ src, u16* __restrict__ dst,
                          int n, const u32* __restrict__ flag) {
    bool f32m = *flag != 0u;
    int i = blockIdx.x * 256 + threadIdx.x;
    if (i < n) dst[i] = f32m ? f2bf(((const float*)src)[i]) : ((const u16*)src)[i];
}

// ------------------------------------------------- GroupNorm stage 1: partials
__launch_bounds__(256)
__global__ void gn_partial(const void* __restrict__ x, float2* __restrict__ partials,
                           const u32* __restrict__ flag) {
    __shared__ float sm[8];
    bool f32m = *flag != 0u;
    const int chunk = GELEM / GN_SPLIT;           // 8192 elements
    size_t base = (size_t)blockIdx.x * chunk;
    float s = 0.f, ss = 0.f;
    if (f32m) {
        const float4* p = (const float4*)((const float*)x + base);
        for (int i = threadIdx.x; i < chunk / 4; i += 256) {
            float4 u = p[i];
            s  += u.x + u.y + u.z + u.w;
            ss += u.x * u.x + u.y * u.y + u.z * u.z + u.w * u.w;
        }
    } else {
        const ushort4* p = (const ushort4*)((const u16*)x + base);
        for (int i = threadIdx.x; i < chunk / 4; i += 256) {
            ushort4 u = p[i];
            float a = bf2f(u.x), b = bf2f(u.y), c = bf2f(u.z), d = bf2f(u.w);
            s  += a + b + c + d;
            ss += a * a + b * b + c * c + d * d;
        }
    }
    int lane = threadIdx.x & 63, w = threadIdx.x >> 6;
    float t = s;
    #pragma unroll
    for (int o = 32; o > 0; o >>= 1) t += __shfl_down(t, o, 64);
    if (lane == 0) sm[w] = t;
    t = ss;
    #pragma unroll
    for (int o = 32; o > 0; o >>= 1) t += __shfl_down(t, o, 64);
    if (lane == 0) sm[4 + w] = t;
    __syncthreads();
    if (threadIdx.x == 0)
        partials[blockIdx.x] = make_float2(sm[0] + sm[1] + sm[2] + sm[3],
                                           sm[4] + sm[5] + sm[6] + sm[7]);
}

// stage 2: fold partials per group, emit per-channel affine (xn = x*sc + sh)
__launch_bounds__(256)
__global__ void gn_coef(const float2* __restrict__ partials, const void* __restrict__ gamma,
                        const void* __restrict__ beta, float2* __restrict__ coef,
                        const u32* __restrict__ flag) {
    bool f32m = *flag != 0u;
    int c = blockIdx.x * 256 + threadIdx.x;
    if (c < CCH) {
        int g = c >> 4;
        float sum = 0.f, sq = 0.f;
        #pragma unroll
        for (int i = 0; i < GN_SPLIT; ++i) {
            float2 p = partials[g * GN_SPLIT + i];
            sum += p.x; sq += p.y;
        }
        float mean = sum * (1.0f / (float)GELEM);
        float var  = fmaxf(sq * (1.0f / (float)GELEM) - mean * mean, 0.0f);
        float rstd = rsqrtf(var + 1e-6f);
        float gm = ldx(gamma, c, f32m), b = ldx(beta, c, f32m);
        float sc = rstd * gm;
        coef[c] = make_float2(sc, b - mean * sc);
    }
}

// GN-apply + transpose: x [c][pos] (poly) -> xn_t [pos][c] (bf16)
__launch_bounds__(256)
__global__ void gn_apply_t(const void* __restrict__ x, const float2* __restrict__ coef,
                           u16* __restrict__ xt, const u32* __restrict__ flag) {
    bool f32m = *flag != 0u;
    __shared__ float tile[64][65];
    int p0 = blockIdx.x * 64, c0 = blockIdx.y * 64;
    int lane = threadIdx.x & 63, rg = threadIdx.x >> 6;
    #pragma unroll 4
    for (int i = 0; i < 16; ++i) {
        int row = rg * 16 + i;
        int c = c0 + row;
        float2 cf = coef[c];
        float v = ldx(x, (size_t)c * NPOS + p0 + lane, f32m);
        tile[row][lane] = v * cf.x + cf.y;
    }
    __syncthreads();
    #pragma unroll 4
    for (int i = 0; i < 16; ++i) {
        int prow = rg * 16 + i;
        xt[(size_t)(p0 + prow) * CCH + c0 + lane] = f2bf(tile[lane][prow]);
    }
}

// --------------------------------------------------------- MFMA TN GEMM
// C[m][n] = sum_k A[m*lda+k] * B[n*ldb+k]
#define EPI_QK  0   // C bf16, += bias[n]
#define EPI_V   1   // C bf16, += bias[m]
#define EPI_OUT 4   // C poly, += bias[m] + resid[idx]

#define LDS_ROW 40  // BK(32) + 8 pad

template<int EPI>
__launch_bounds__(256)
__global__ void mfma_gemm(const u16* __restrict__ A, const u16* __restrict__ B,
                          void* __restrict__ C, const u16* __restrict__ bias,
                          const void* __restrict__ resid, const u32* __restrict__ flag,
                          int lda, int ldb, int ldc, int K) {
    __shared__ u16 As[128 * LDS_ROW];
    __shared__ u16 Bs[128 * LDS_ROW];
    const int tid = threadIdx.x;
    const u16* Ab = A + (size_t)blockIdx.y * 128 * lda;
    const u16* Bb = B + (size_t)blockIdx.x * 128 * ldb;

    const int srow = tid >> 2;
    const int sch  = (tid & 3) * 8;

    const int wave = tid >> 6, lane = tid & 63;
    const int wm = (wave >> 1) * 64, wn = (wave & 1) * 64;
    const int l15 = lane & 15, quad = lane >> 4;

    floatx4 acc[4][4] = {};

    for (int kk = 0; kk < K; kk += 32) {
        uint4 a0 = *(const uint4*)(Ab + (size_t)srow * lda + kk + sch);
        uint4 a1 = *(const uint4*)(Ab + (size_t)(srow + 64) * lda + kk + sch);
        uint4 b0 = *(const uint4*)(Bb + (size_t)srow * ldb + kk + sch);
        uint4 b1 = *(const uint4*)(Bb + (size_t)(srow + 64) * ldb + kk + sch);
        __syncthreads();
        *(uint4*)&As[srow * LDS_ROW + sch]        = a0;
        *(uint4*)&As[(srow + 64) * LDS_ROW + sch] = a1;
        *(uint4*)&Bs[srow * LDS_ROW + sch]        = b0;
        *(uint4*)&Bs[(srow + 64) * LDS_ROW + sch] = b1;
        __syncthreads();
        short8 af[4], bf[4];
        #pragma unroll
        for (int mi = 0; mi < 4; ++mi)
            af[mi] = *(const short8*)&As[(wm + mi * 16 + l15) * LDS_ROW + quad * 8];
        #pragma unroll
        for (int ni = 0; ni < 4; ++ni)
            bf[ni] = *(const short8*)&Bs[(wn + ni * 16 + l15) * LDS_ROW + quad * 8];
        #pragma unroll
        for (int mi = 0; mi < 4; ++mi)
            #pragma unroll
            for (int ni = 0; ni < 4; ++ni)
                acc[mi][ni] = __builtin_amdgcn_mfma_f32_16x16x32_bf16(
                    af[mi], bf[ni], acc[mi][ni], 0, 0, 0);
    }

    const bool f32m = (EPI == EPI_OUT) ? (*flag != 0u) : false;
    const int m_base = blockIdx.y * 128 + wm;
    const int n_base = blockIdx.x * 128 + wn;

    #pragma unroll
    for (int mi = 0; mi < 4; ++mi) {
        #pragma unroll
        for (int ni = 0; ni < 4; ++ni) {
            int n = n_base + ni * 16 + l15;
            float bn = (EPI == EPI_QK) ? bf2f(bias[n]) : 0.0f;
            #pragma unroll
            for (int r = 0; r < 4; ++r) {
                int m = m_base + mi * 16 + quad * 4 + r;
                float v = acc[mi][ni][r];
                size_t idx = (size_t)m * ldc + n;
                if (EPI == EPI_QK) {
                    ((u16*)C)[idx] = f2bf(v + bn);
                } else if (EPI == EPI_V) {
                    ((u16*)C)[idx] = f2bf(v + bf2f(bias[m]));
                } else {  // EPI_OUT
                    float r2 = v + bf2f(bias[m]) + ldx(resid, idx, f32m);
                    if (f32m) ((float*)C)[idx] = r2;
                    else      ((u16*)C)[idx]   = f2bf(r2);
                }
            }
        }
    }
}

// --------------------------------------------------------- Flash attention
// One block per (q-tile of 64 rows, frame). 8 waves / 512 threads.
// qt,kt: [tok][c] bf16 (c-contig).  vt: [c][pos] bf16 (pos-contig).
// O = softmax(q k^T * scale) v, written as obuf[pos][c] bf16.
#define QT 64
#define KT 64
__launch_bounds__(512, 2)
__global__ void flash_attn(const u16* __restrict__ qt, const u16* __restrict__ kt,
                           const u16* __restrict__ vt, u16* __restrict__ obuf) {
    __shared__ __align__(16) u16  Qs[QT][520];     // 64x512 + pad8
    __shared__ __align__(16) float Ss[QT][68];     // S tile f32 + pad4
    __shared__ __align__(16) u16  Ps[QT][72];      // P tile bf16 + pad8
    __shared__ float mrow[QT], lrow[QT], arow[QT];

    const int q0 = blockIdx.x * QT;
    const int f  = blockIdx.y;
    const int tid = threadIdx.x;
    const int wave = tid >> 6, lane = tid & 63;
    const int l15 = lane & 15, quad = lane >> 4;
    const float scale = 0.044194173824159216f;  // 512^-0.5

    // stage Q tile: 64 rows x 512 c = 4096 uint4 / 512 threads = 8 each
    {
        const u16* qbase = qt + ((size_t)(f * NTOK + q0)) * CCH;
        #pragma unroll
        for (int i = 0; i < 8; ++i) {
            int li = i * 512 + tid;
            int row = li >> 6, c8 = (li & 63) * 8;
            *(uint4*)&Qs[row][c8] = *(const uint4*)(qbase + (size_t)row * CCH + c8);
        }
    }
    if (tid < QT) { mrow[tid] = -3.0e38f; lrow[tid] = 0.0f; }
    __syncthreads();   // Q tile + m/l init visible to all waves (was the NaN race)

    floatx4 acc[4][4] = {};            // wave's 64q x 64c O slice
    const int cbase = wave * 64;
    const u16* kfrm = kt + (size_t)f * NTOK * CCH;
    const u16* vfrm = vt + (size_t)f * NTOK;

    for (int k0 = 0; k0 < NTOK; k0 += KT) {
        // ---- S = Q K^T : each wave computes two 16x16 tiles of the 64x64 S
        floatx4 sacc0 = {0.f, 0.f, 0.f, 0.f}, sacc1 = {0.f, 0.f, 0.f, 0.f};
        const int i0 = wave * 2, i1 = wave * 2 + 1;
        const int sm0 = i0 >> 2, sn0 = i0 & 3, sm1 = i1 >> 2, sn1 = i1 & 3;
        #pragma unroll
        for (int cc = 0; cc < CCH; cc += 32) {
            short8 a0 = *(const short8*)&Qs[sm0 * 16 + l15][cc + quad * 8];
            short8 b0 = *(const short8*)(kfrm + (size_t)(k0 + sn0 * 16 + l15) * CCH + cc + quad * 8);
            sacc0 = __builtin_amdgcn_mfma_f32_16x16x32_bf16(a0, b0, sacc0, 0, 0, 0);
            short8 a1 = *(const short8*)&Qs[sm1 * 16 + l15][cc + quad * 8];
            short8 b1 = *(const short8*)(kfrm + (size_t)(k0 + sn1 * 16 + l15) * CCH + cc + quad * 8);
            sacc1 = __builtin_amdgcn_mfma_f32_16x16x32_bf16(a1, b1, sacc1, 0, 0, 0);
        }
        __syncthreads();   // prev iteration's Ss/Ps consumers done
        #pragma unroll
        for (int r = 0; r < 4; ++r) {
            Ss[sm0 * 16 + quad * 4 + r][sn0 * 16 + l15] = sacc0[r];
            Ss[sm1 * 16 + quad * 4 + r][sn1 * 16 + l15] = sacc1[r];
        }
        __syncthreads();   // Ss complete

        // ---- online softmax: wave w owns rows 8w..8w+7; 8 lanes per row
        {
            int row = wave * 8 + (lane >> 3);
            int j = lane & 7;
            float v[8];
            float mx = -3.0e38f;
            #pragma unroll
            for (int c8 = 0; c8 < 8; ++c8) {
                v[c8] = Ss[row][c8 * 8 + j] * scale;
                mx = fmaxf(mx, v[c8]);
            }
            mx = fmaxf(mx, __shfl_xor(mx, 1, 64));
            mx = fmaxf(mx, __shfl_xor(mx, 2, 64));
            mx = fmaxf(mx, __shfl_xor(mx, 4, 64));
            float m_old = mrow[row];
            float m_new = fmaxf(m_old, mx);
            float sum = 0.f;
            #pragma unroll
            for (int c8 = 0; c8 < 8; ++c8) {
                float p = __expf(v[c8] - m_new);
                Ps[row][c8 * 8 + j] = f2bf(p);
                sum += p;
            }
            sum += __shfl_xor(sum, 1, 64);
            sum += __shfl_xor(sum, 2, 64);
            sum += __shfl_xor(sum, 4, 64);
            if (j == 0) {
                float alpha = __expf(m_old - m_new);
                arow[row] = alpha;
                mrow[row] = m_new;
                lrow[row] = lrow[row] * alpha + sum;
            }
        }
        __syncthreads();   // Ps/arow ready

        // ---- O = O*alpha + P V^T (wave's 64-c slice)
        float al[4][4];
        #pragma unroll
        for (int mi = 0; mi < 4; ++mi)
            #pragma unroll
            for (int r = 0; r < 4; ++r)
                al[mi][r] = arow[mi * 16 + quad * 4 + r];
        #pragma unroll
        for (int mi = 0; mi < 4; ++mi)
            #pragma unroll
            for (int ni = 0; ni < 4; ++ni)
                #pragma unroll
                for (int r = 0; r < 4; ++r)
                    acc[mi][ni][r] *= al[mi][r];
        #pragma unroll
        for (int ks = 0; ks < 2; ++ks) {
            short8 af[4], bf[4];
            #pragma unroll
            for (int mi = 0; mi < 4; ++mi)
                af[mi] = *(const short8*)&Ps[mi * 16 + l15][ks * 32 + quad * 8];
            #pragma unroll
            for (int ni = 0; ni < 4; ++ni)
                bf[ni] = *(const short8*)(vfrm + (size_t)(cbase + ni * 16 + l15) * NPOS
                                          + k0 + ks * 32 + quad * 8);
            #pragma unroll
            for (int mi = 0; mi < 4; ++mi)
                #pragma unroll
                for (int ni = 0; ni < 4; ++ni)
                    acc[mi][ni] = __builtin_amdgcn_mfma_f32_16x16x32_bf16(
                        af[mi], bf[ni], acc[mi][ni], 0, 0, 0);
        }
    }

    // ---- epilogue: O /= l, store obuf[pos][c]
    __syncthreads();
    #pragma unroll
    for (int mi = 0; mi < 4; ++mi) {
        float li[4];
        #pragma unroll
        for (int r = 0; r < 4; ++r)
            li[r] = 1.0f / lrow[mi * 16 + quad * 4 + r];
        #pragma unroll
        for (int ni = 0; ni < 4; ++ni) {
            #pragma unroll
            for (int r = 0; r < 4; ++r) {
                int row = mi * 16 + quad * 4 + r;
                size_t idx = (size_t)(f * NTOK + q0 + row) * CCH + cbase + ni * 16 + l15;
                obuf[idx] = f2bf(acc[mi][ni][r] * li[r]);
            }
        }
    }
}

// ---------------------------------------------------------------- launcher
extern "C" void kernel_launch(void* const* d_in, const int* in_sizes, int n_in,
                              void* d_out, int out_size, void* d_ws, size_t ws_size,
                              hipStream_t stream) {
    const void* x   = d_in[0];
    const void* gam = d_in[1];
    const void* bet = d_in[2];

    // Workspace (<= 68 MiB):
    //   [0,4K) coef  [4K,+8K) partials  [12352) flag
    //   [16K,+2Mi) bf16 weights  [~2.1Mi,+4K) bf16 biases
    //   [4Mi)  xnt 16Mi (reused as obuf)   [20Mi) qt   [36Mi) kt   [52Mi) vt
    char* ws = (char*)d_ws;
    float2* coef     = (float2*)(ws);
    float2* partials = (float2*)(ws + 4096);
    u32*    flag     = (u32*)(ws + 12352);
    u16* cw[4] = { (u16*)(ws + 16384),              (u16*)(ws + 16384 +  524288ull),
                   (u16*)(ws + 16384 + 1048576ull), (u16*)(ws + 16384 + 1572864ull) };
    u16* cb[4] = { (u16*)(ws + 2113536ull),        (u16*)(ws + 2113536ull + 1024),
                   (u16*)(ws + 2113536ull + 2048), (u16*)(ws + 2113536ull + 3072) };
    u16*  xnt  = (u16*)(ws + (4ull  << 20));
    u16*  qt   = (u16*)(ws + (20ull << 20));
    u16*  kt   = (u16*)(ws + (36ull << 20));
    u16*  vt   = (u16*)(ws + (52ull << 20));
    u16*  obuf = xnt;

    detect_dtype<<<1, 256, 0, stream>>>((const u32*)x, flag);
    for (int i = 0; i < 4; ++i) {
        conv_bf16<<<1024, 256, 0, stream>>>(d_in[3 + 2 * i], cw[i], 262144, flag);
        conv_bf16<<<2, 256, 0, stream>>>(d_in[4 + 2 * i], cb[i], 512, flag);
    }
    gn_partial<<<NGRP * GN_SPLIT, 256, 0, stream>>>(x, partials, flag);
    gn_coef<<<2, 256, 0, stream>>>(partials, gam, bet, coef, flag);
    gn_apply_t<<<dim3(NPOS / 64, CCH / 64), 256, 0, stream>>>(x, coef, xnt, flag);

    // q,k: C[pos][cout]
    dim3 gqk(CCH / 128, NPOS / 128);      // (4, 128)
    mfma_gemm<EPI_QK><<<gqk, 256, 0, stream>>>(xnt, cw[0], qt, cb[0], nullptr, flag,
                                               CCH, CCH, CCH, CCH);
    mfma_gemm<EPI_QK><<<gqk, 256, 0, stream>>>(xnt, cw[1], kt, cb[1], nullptr, flag,
                                               CCH, CCH, CCH, CCH);
    // v: C[cout][pos]
    dim3 gv(NPOS / 128, CCH / 128);       // (128, 4)
    mfma_gemm<EPI_V><<<gv, 256, 0, stream>>>(cw[2], xnt, vt, cb[2], nullptr, flag,
                                             CCH, CCH, NPOS, CCH);

    // fused attention: grid (q-tiles, frames)
    flash_attn<<<dim3(NTOK / QT, NFRM), 512, 0, stream>>>(qt, kt, vt, obuf);

    // out: C[cout][pos] = Wo . O + bo + x, poly store
    dim3 go(NPOS / 128, CCH / 128);       // (128, 4)
    mfma_gemm<EPI_OUT><<<go, 256, 0, stream>>>(cw[3], obuf, d_out, cb[3], x, flag,
                                               CCH, CCH, NPOS, CCH);
}